// Round 1
// 2303.007 us; speedup vs baseline: 1.2958x; 1.2958x over previous
//
#include <hip/hip_runtime.h>
#include <hip/hip_bf16.h>
#include <stdint.h>
#include <stdio.h>

#define L_SEQ 8192
#define DIM_ 2048
#define HK_ 16
#define HV_ 32
#define DK_ 128
#define DV_ 128
#define CONV_DIM_ 8192
#define EPS_F 1e-6f

typedef __bf16 bf16;
typedef __bf16 bf16x8 __attribute__((ext_vector_type(8)));
typedef __bf16 bf16x4 __attribute__((ext_vector_type(4)));
typedef __bf16 bf16x2 __attribute__((ext_vector_type(2)));
typedef float f32x4 __attribute__((ext_vector_type(4)));

// ---------------------------------------------------------------- helpers
__device__ __forceinline__ void load_lds16(const void* g, void* l) {
  __builtin_amdgcn_global_load_lds((const __attribute__((address_space(1))) uint32_t*)g,
                                   (__attribute__((address_space(3))) uint32_t*)l,
                                   16, 0, 0);
}

// ---------------------------------------------------------------- fp32 -> bf16 convert (x)
__global__ __launch_bounds__(256) void k_convert(const float4* __restrict__ src,
                                                 bf16x4* __restrict__ dst, int n4) {
  int i = blockIdx.x * 256 + threadIdx.x;
  if (i >= n4) return;
  float4 v = src[i];
  bf16x4 o;
  o[0] = (bf16)v.x; o[1] = (bf16)v.y; o[2] = (bf16)v.z; o[3] = (bf16)v.w;
  dst[i] = o;
}

// ---------------------------------------------------------------- W [K][ldW] fp32 (cols n_off..n_off+Nout) -> Wt [Nout][K] bf16
__global__ __launch_bounds__(256) void k_transpose_cvt(const float* __restrict__ W,
                                                       bf16* __restrict__ Wt, int K, int ldW,
                                                       int n_off) {
  __shared__ float tile[32][33];
  int n0 = blockIdx.x * 32, k0 = blockIdx.y * 32;
  int cx = threadIdx.x & 31, ry = threadIdx.x >> 5;  // ry in 0..7
#pragma unroll
  for (int i = 0; i < 4; i++)
    tile[ry + i * 8][cx] = W[(size_t)(k0 + ry + i * 8) * ldW + n_off + n0 + cx];
  __syncthreads();
#pragma unroll
  for (int i = 0; i < 4; i++) {
    int r = ry + i * 8;
    Wt[(size_t)(n0 + r) * K + k0 + cx] = (bf16)tile[cx][r];
  }
}

// ---------------------------------------------------------------- bf16 MFMA GEMM: C[M,N] = A[M,K] @ Bt[N,K]^T
template <int BF16_OUT>
__global__ __launch_bounds__(256) void k_gemm_bt(const bf16* __restrict__ A,
                                                 const bf16* __restrict__ Bt,
                                                 void* __restrict__ Cout,
                                                 int M, int N, int K) {
  __shared__ __align__(16) bf16 la[4096];  // [kchunk 4][row 128][8]
  __shared__ __align__(16) bf16 lb[4096];
  const int tid = threadIdx.x;
  const int lane = tid & 63;
  const int wave = tid >> 6;
  const int wm = wave >> 1, wn = wave & 1;
  const int bm = blockIdx.y << 7, bn = blockIdx.x << 7;

  f32x4 acc[4][4];
#pragma unroll
  for (int i = 0; i < 4; i++)
#pragma unroll
    for (int j = 0; j < 4; j++) acc[i][j] = (f32x4){0.f, 0.f, 0.f, 0.f};

  const bf16* Ag = A + (size_t)(bm + lane) * K + wave * 8;
  const bf16* Bg = Bt + (size_t)(bn + lane) * K + wave * 8;
  bf16* lA = la + wave * 1024;
  bf16* lB = lb + wave * 1024;
  const size_t rowskip = (size_t)64 * K;

  const int chunk = lane >> 4;
  const int rr = lane & 15;
  const bf16* fa = la + chunk * 1024 + (wm * 64 + rr) * 8;
  const bf16* fb = lb + chunk * 1024 + (wn * 64 + rr) * 8;

  for (int k0 = 0; k0 < K; k0 += 32) {
    __syncthreads();
    load_lds16(Ag + k0, lA);
    load_lds16(Ag + k0 + rowskip, lA + 512);
    load_lds16(Bg + k0, lB);
    load_lds16(Bg + k0 + rowskip, lB + 512);
    __syncthreads();
    bf16x8 af[4], bfr[4];
#pragma unroll
    for (int i = 0; i < 4; i++) {
      af[i] = *(const bf16x8*)(fa + i * 16 * 8);
      bfr[i] = *(const bf16x8*)(fb + i * 16 * 8);
    }
#pragma unroll
    for (int mi = 0; mi < 4; mi++)
#pragma unroll
      for (int ni = 0; ni < 4; ni++)
        acc[mi][ni] = __builtin_amdgcn_mfma_f32_16x16x32_bf16(af[mi], bfr[ni], acc[mi][ni], 0, 0, 0);
  }

  const int col = bn + wn * 64 + rr;
  const int row0 = bm + wm * 64 + (lane >> 4) * 4;
#pragma unroll
  for (int mi = 0; mi < 4; mi++)
#pragma unroll
    for (int ni = 0; ni < 4; ni++)
#pragma unroll
      for (int r = 0; r < 4; r++) {
        int rowi = row0 + mi * 16 + r;
        int coli = col + ni * 16;
        if (BF16_OUT)
          ((bf16*)Cout)[(size_t)rowi * N + coli] = (bf16)acc[mi][ni][r];
        else
          ((float*)Cout)[(size_t)rowi * N + coli] = acc[mi][ni][r];
      }
}

// ---------------------------------------------------------------- gates: a,b GEMV + g(log-decay)/beta
// gb layout: [t][0..31]=g (LOG decay, nats), [t][32..63]=beta
__global__ __launch_bounds__(256) void k_gates(const float* __restrict__ x,
                                               const float* __restrict__ Wa,
                                               const float* __restrict__ Wb,
                                               const float* __restrict__ A_log,
                                               const float* __restrict__ dt_bias,
                                               float* __restrict__ gb) {
  int t = blockIdx.x * 4 + (threadIdx.x >> 6);
  int lane = threadIdx.x & 63;
  int h = lane & 31;
  int isB = lane >> 5;
  const float* W = isB ? Wb : Wa;
  const float* xr = x + (size_t)t * DIM_;
  float a0 = 0.f, a1 = 0.f, a2 = 0.f, a3 = 0.f;
  for (int kk = 0; kk < DIM_; kk += 4) {
    float4 xv = *(const float4*)(xr + kk);
    a0 += xv.x * W[(kk + 0) * 32 + h];
    a1 += xv.y * W[(kk + 1) * 32 + h];
    a2 += xv.z * W[(kk + 2) * 32 + h];
    a3 += xv.w * W[(kk + 3) * 32 + h];
  }
  float acc = (a0 + a1) + (a2 + a3);
  if (isB) {
    gb[(size_t)t * 64 + 32 + h] = 1.f / (1.f + expf(-acc));
  } else {
    float ag = acc + dt_bias[h];
    float sp = (ag > 20.f) ? ag : log1pf(expf(ag));
    gb[(size_t)t * 64 + h] = -expf(A_log[h]) * sp;  // log decay (<= 0)
  }
}

// ---------------------------------------------------------------- conv + silu (+ l2norm for q/k)
template <int IS_V>
__global__ __launch_bounds__(128) void k_conv(const bf16* __restrict__ src,
                                              const float* __restrict__ conv_w,
                                              const int* __restrict__ cu, int nseq,
                                              bf16* __restrict__ qn, bf16* __restrict__ kn,
                                              bf16* __restrict__ v) {
  __shared__ float red[2];
  int t = blockIdx.x;
  int grp = blockIdx.y;  // 0..31
  int c = grp * 128 + threadIdx.x;  // column within this half
  int start = 0;
  for (int s = 0; s < nseq; s++) {
    int a = cu[s];
    if (a <= t) start = a;
  }
  float4 w = *(const float4*)(conv_w + (size_t)(c + (IS_V ? 4096 : 0)) * 4);
  float accv = 0.f;
#pragma unroll
  for (int i = 0; i < 4; i++) {
    int tp = t - 3 + i;
    if (tp >= start) {
      float wv = (i == 0) ? w.x : (i == 1) ? w.y : (i == 2) ? w.z : w.w;
      accv += wv * (float)src[(size_t)tp * 4096 + c];
    }
  }
  float val = accv / (1.f + __expf(-accv));  // silu
  if (IS_V) {
    v[((size_t)t * HV_ + grp) * DV_ + threadIdx.x] = (bf16)val;
  } else {
    float ss = val * val;
#pragma unroll
    for (int off = 1; off < 64; off <<= 1) ss += __shfl_xor(ss, off);
    if ((threadIdx.x & 63) == 0) red[threadIdx.x >> 6] = ss;
    __syncthreads();
    float tot = red[0] + red[1];
    float scale = rsqrtf(tot + EPS_F);
    if (grp < 16) {
      scale *= 0.08838834764831845f;  // DK^-0.5
      qn[((size_t)t * HK_ + grp) * DK_ + threadIdx.x] = (bf16)(val * scale);
    } else {
      kn[((size_t)t * HK_ + (grp - 16)) * DK_ + threadIdx.x] = (bf16)(val * scale);
    }
  }
}

// ================================================================ chunked gated delta scan (WY form, MFMA)
// Per chunk of C=64 steps (per head, per 64-wide dv half):
//   A[t][s] = b_t (k_t.k_s) 2^(G2t-G2s)   (s<t)          [KK^T mfma + mask]
//   (I+A) U = R,   R[t] = b_t (V[t] - 2^G2t * (K S0)[t])  [fwd substitution, fp32]
//   O[t]   = 2^G2t * (Q S0)[t] + (M U)[t], M[t][s] = (q_t.k_s) 2^(G2t-G2s), s<=t
//   S_new  = 2^G2c * S0 + sum_s 2^(G2c-G2s) k_s U[s]^T
// G2 = inclusive cumsum of log2-decay within chunk; all 2^x factors <= 1.
// LDS tiles XOR-swizzled (blk ^= row&7 on 16B blocks); staged with
// global_load_lds + pre-swizzled global source (linear LDS dest).

#define SA_LD 68
#define SUF_LD 65

__device__ __forceinline__ bf16x8 frag256(const bf16* base, int tile, int kk, int lane) {
  int row = tile * 16 + (lane & 15);
  int blk = kk * 4 + (lane >> 4);  // 0..15
  int byte = row * 256 + (((blk & 8) | ((blk & 7) ^ (row & 7))) << 4);
  return *(const bf16x8*)((const char*)base + byte);
}
__device__ __forceinline__ bf16x8 frag128(const bf16* base, int tile, int kk, int lane) {
  int row = tile * 16 + (lane & 15);
  int blk = kk * 4 + (lane >> 4);  // 0..7
  int byte = row * 128 + ((blk ^ (row & 7)) << 4);
  return *(const bf16x8*)((const char*)base + byte);
}
__device__ __forceinline__ bf16x8 ld256v(const bf16* base, int row, int blk) {
  int byte = row * 256 + (((blk & 8) | ((blk & 7) ^ (row & 7))) << 4);
  return *(const bf16x8*)((const char*)base + byte);
}
__device__ __forceinline__ void st128e(bf16* base, int row, int col, float v) {
  int byte = row * 128 + ((((col >> 3) ^ (row & 7)) << 4)) + (col & 7) * 2;
  *(bf16*)((char*)base + byte) = (bf16)v;
}
__device__ __forceinline__ float ld128e(const bf16* base, int row, int col) {
  int byte = row * 128 + ((((col >> 3) ^ (row & 7)) << 4)) + (col & 7) * 2;
  return (float)*(const bf16*)((const char*)base + byte);
}
__device__ __forceinline__ void st256e(bf16* base, int row, int col, float v) {
  int blk = col >> 3;  // 0..15
  int byte = row * 256 + (((blk & 8) | ((blk & 7) ^ (row & 7))) << 4) + (col & 7) * 2;
  *(bf16*)((char*)base + byte) = (bf16)v;
}

__global__ __launch_bounds__(256, 1) void k_scan_chunk(const bf16* __restrict__ qn,
                                                       const bf16* __restrict__ kn,
                                                       const bf16* __restrict__ v,
                                                       const float* __restrict__ gb,
                                                       const int* __restrict__ cu,
                                                       bf16* __restrict__ o) {
  __shared__ __align__(16) bf16 sK[64 * 128];    // [t][dk]  swz256
  __shared__ __align__(16) bf16 sQ[64 * 128];    // [t][dk]  swz256
  __shared__ __align__(16) bf16 sKt[128 * 64];   // [dk][t]  swz128, scaled 2^(G2c-G2t)
  __shared__ __align__(16) bf16 sSt[64 * 128];   // [dv][dk] swz256, state operand copy
  __shared__ __align__(16) bf16 sV[64 * 64];     // [t][dv]  swz128
  __shared__ __align__(16) bf16 sM[64 * 64];     // [t][s]   swz128
  __shared__ __align__(16) bf16 sUt[64 * 64];    // [dv][s]  swz128
  __shared__ float sA[64 * SA_LD];               // [t][s]   fp32
  __shared__ float sUf[64 * SUF_LD];             // [t][dv]  fp32 (R then U)
  __shared__ float sG2[2][64], sB[2][64], sEg[2][64];

  const int h = blockIdx.y;
  const int hk = h >> 1;
  const int seq = blockIdx.z;
  const int dv0 = blockIdx.x * 64;
  const int tid = threadIdx.x;
  const int lane = tid & 63;
  const int wave = tid >> 6;
  const int w16 = wave * 16;
  const int t0 = cu[seq], t1 = cu[seq + 1];
  if (t0 >= t1) return;

  // fp32 state in regs, MFMA C/D layout: rows dk=(2w+a)*16+(lane>>4)*4+r, cols dv=c*16+(lane&15)
  f32x4 St[2][4];
#pragma unroll
  for (int a = 0; a < 2; a++)
#pragma unroll
    for (int c = 0; c < 4; c++) St[a][c] = (f32x4){0.f, 0.f, 0.f, 0.f};
#pragma unroll
  for (int i = 0; i < 4; i++) ((float4*)sSt)[tid * 4 + i] = (float4){0.f, 0.f, 0.f, 0.f};

  auto stageKQV = [&](int ts) {
#pragma unroll
    for (int it = 0; it < 4; it++) {
      int Bx = (wave * 4 + it) * 64 + lane;  // 16B block index (1024 total)
      int r = Bx >> 4, bq = Bx & 15;
      int tr = ts + r; if (tr >= t1) tr = t1 - 1;
      int bs = (bq & 8) | ((bq & 7) ^ (r & 7));  // pre-swizzled global block
      size_t go = (size_t)tr * (HK_ * DK_) + hk * DK_ + bs * 8;
      load_lds16(kn + go, (char*)sK + (size_t)(wave * 4 + it) * 1024);
      load_lds16(qn + go, (char*)sQ + (size_t)(wave * 4 + it) * 1024);
    }
#pragma unroll
    for (int it = 0; it < 2; it++) {
      int Bx = (wave * 2 + it) * 64 + lane;  // 512 blocks
      int r = Bx >> 3, bq = Bx & 7;
      int tr = ts + r; if (tr >= t1) tr = t1 - 1;
      int bs = bq ^ (r & 7);
      load_lds16(v + (size_t)tr * (HV_ * DV_) + h * DV_ + dv0 + bs * 8,
                 (char*)sV + (size_t)(wave * 2 + it) * 1024);
    }
  };

  auto prefix = [&](int ts, int pb) {  // one wave: load g/beta, log2 cumsum
    int tr = ts + lane;
    float gv = 0.f, bv = 0.f;
    if (tr < t1) {
      gv = gb[(size_t)tr * 64 + h] * 1.44269504088896f;
      bv = gb[(size_t)tr * 64 + 32 + h];
    }
    float ps = gv;
#pragma unroll
    for (int off = 1; off < 64; off <<= 1) {
      float tmp = __shfl_up(ps, off);
      if (lane >= off) ps += tmp;
    }
    sG2[pb][lane] = ps;
    sB[pb][lane] = bv;
    sEg[pb][lane] = exp2f(ps);
  };

  int buf = 0;
  stageKQV(t0);
  if (wave == 0) prefix(t0, 0);
  __syncthreads();

  bool first = true;
  for (int ts = t0; ts < t1; ts += 64) {
    const bool haveNext = (ts + 64 < t1);
    const float* G2 = sG2[buf];
    const float* Bt = sB[buf];
    const float* Eg = sEg[buf];

    // ---- phase 1: KK^T, QK^T (lower tiles), K*S0, Q*S0 ----
    f32x4 aKK[4], aQK[4], aKS[4], aQS[4];
#pragma unroll
    for (int c = 0; c < 4; c++) {
      aKK[c] = (f32x4){0.f, 0.f, 0.f, 0.f};
      aQK[c] = (f32x4){0.f, 0.f, 0.f, 0.f};
      aKS[c] = (f32x4){0.f, 0.f, 0.f, 0.f};
      aQS[c] = (f32x4){0.f, 0.f, 0.f, 0.f};
    }
#pragma unroll
    for (int kk = 0; kk < 4; kk++) {
      bf16x8 ak = frag256(sK, wave, kk, lane);
      bf16x8 aq = frag256(sQ, wave, kk, lane);
#pragma unroll
      for (int c = 0; c < 4; c++) {
        if (c <= wave) {
          bf16x8 bk = frag256(sK, c, kk, lane);
          aKK[c] = __builtin_amdgcn_mfma_f32_16x16x32_bf16(ak, bk, aKK[c], 0, 0, 0);
          aQK[c] = __builtin_amdgcn_mfma_f32_16x16x32_bf16(aq, bk, aQK[c], 0, 0, 0);
        }
        if (!first) {
          bf16x8 bs = frag256(sSt, c, kk, lane);
          aKS[c] = __builtin_amdgcn_mfma_f32_16x16x32_bf16(ak, bs, aKS[c], 0, 0, 0);
          aQS[c] = __builtin_amdgcn_mfma_f32_16x16x32_bf16(aq, bs, aQS[c], 0, 0, 0);
        }
      }
    }

    // ---- mask/scale -> sA (fp32), sM (bf16); R -> sUf ----
    const float G2c = G2[63];
    {
      const int li = lane & 15, lh = lane >> 4;
      float g2s[4];
#pragma unroll
      for (int c = 0; c < 4; c++) g2s[c] = G2[c * 16 + li];
#pragma unroll
      for (int r = 0; r < 4; r++) {
        const int t = w16 + lh * 4 + r;
        const float g2t = G2[t], btv = Bt[t], egt = Eg[t];
#pragma unroll
        for (int c = 0; c < 4; c++) {
          const int s = c * 16 + li;
          const float e = exp2f(g2t - g2s[c]);
          sA[t * SA_LD + s] = (s < t) ? btv * e * aKK[c][r] : 0.f;
          st128e(sM, t, s, (s <= t) ? e * aQK[c][r] : 0.f);
          sUf[t * SUF_LD + s] = btv * (ld128e(sV, t, s) - egt * aKS[c][r]);
        }
      }
    }
    // ---- T1: sKt[dk][t] = K[t][dk] * 2^(G2c - G2t) ----
    {
      const int t = lane;
      const float sc = exp2f(G2c - G2[t]);
#pragma unroll
      for (int i = 0; i < 4; i++) {
        int dk0 = wave * 32 + i * 8;
        bf16x8 kv = ld256v(sK, t, wave * 4 + i);
#pragma unroll
        for (int j = 0; j < 8; j++) st128e(sKt, dk0 + j, t, (float)kv[j] * sc);
      }
    }
    __syncthreads();

    // ---- issue next-chunk staging early (hides HBM under substitution) ----
    if (haveNext) {
      stageKQV(ts + 64);
      if (wave == 3) prefix(ts + 64, buf ^ 1);
    }

    // ---- forward substitution: (I+A) U = R, 16-row blocks ----
    for (int b = 0; b < 4; b++) {
      if (wave == 0) {
        const int b16o = b * 16;
        float u[16];
#pragma unroll
        for (int i = 0; i < 16; i++) {
          const int t = b16o + i;
          float x = sUf[t * SUF_LD + lane];
          const float* Ar = &sA[t * SA_LD + b16o];
#pragma unroll
          for (int j = 0; j < i; j++) x -= Ar[j] * u[j];
          u[i] = x;
          sUf[t * SUF_LD + lane] = x;
        }
      }
      __syncthreads();
      if (b < 3) {
        if (wave < 3) {  // wave 3 may be doing next-chunk prefix
          const int b16o = b * 16;
          float us[16];
#pragma unroll
          for (int j = 0; j < 16; j++) us[j] = sUf[(b16o + j) * SUF_LD + lane];
          for (int t = b16o + 16 + wave; t < 64; t += 3) {
            float x = sUf[t * SUF_LD + lane];
            const float* Ar = &sA[t * SA_LD + b16o];
#pragma unroll
            for (int j = 0; j < 16; j++) x -= Ar[j] * us[j];
            sUf[t * SUF_LD + lane] = x;
          }
        }
        __syncthreads();
      }
    }

    // ---- T2: sUt[dv][s] = U[s][dv] (bf16) ----
    {
      const int s = lane;
#pragma unroll
      for (int i = 0; i < 16; i++) {
        int dvv = wave * 16 + i;
        st128e(sUt, dvv, s, sUf[s * SUF_LD + dvv]);
      }
    }
    __syncthreads();

    // ---- output: O = 2^G2t * (Q S0) + M U ----
    f32x4 aO[4];
#pragma unroll
    for (int c = 0; c < 4; c++)
#pragma unroll
      for (int r = 0; r < 4; r++)
        aO[c][r] = Eg[w16 + (lane >> 4) * 4 + r] * aQS[c][r];
#pragma unroll
    for (int kk = 0; kk < 2; kk++) {
      bf16x8 am = frag128(sM, wave, kk, lane);
#pragma unroll
      for (int c = 0; c < 4; c++) {
        bf16x8 bu = frag128(sUt, c, kk, lane);
        aO[c] = __builtin_amdgcn_mfma_f32_16x16x32_bf16(am, bu, aO[c], 0, 0, 0);
      }
    }
#pragma unroll
    for (int r = 0; r < 4; r++) {
      const int t = w16 + (lane >> 4) * 4 + r;
      if (ts + t < t1) {
#pragma unroll
        for (int c = 0; c < 4; c++)
          o[((size_t)(ts + t) * HV_ + h) * DV_ + dv0 + c * 16 + (lane & 15)] = (bf16)aO[c][r];
      }
    }

    // ---- state update: S = 2^G2c * S + Kt' U ----
    {
      const float egc = Eg[63];
#pragma unroll
      for (int a = 0; a < 2; a++)
#pragma unroll
        for (int c = 0; c < 4; c++)
#pragma unroll
          for (int r = 0; r < 4; r++) St[a][c][r] *= egc;
#pragma unroll
      for (int kk = 0; kk < 2; kk++) {
#pragma unroll
        for (int a = 0; a < 2; a++) {
          bf16x8 akt = frag128(sKt, 2 * wave + a, kk, lane);
#pragma unroll
          for (int c = 0; c < 4; c++) {
            bf16x8 bu = frag128(sUt, c, kk, lane);
            St[a][c] = __builtin_amdgcn_mfma_f32_16x16x32_bf16(akt, bu, St[a][c], 0, 0, 0);
          }
        }
      }
      // bf16 operand copy for next chunk's K*S0 / Q*S0
#pragma unroll
      for (int a = 0; a < 2; a++)
#pragma unroll
        for (int c = 0; c < 4; c++)
#pragma unroll
          for (int r = 0; r < 4; r++) {
            int dk = (2 * wave + a) * 16 + (lane >> 4) * 4 + r;
            int dvv = c * 16 + (lane & 15);
            st256e(sSt, dvv, dk, St[a][c][r]);
          }
    }
    first = false;
    buf ^= 1;
    __syncthreads();  // sSt/sG2[buf] visible; staged DMA drained
  }
}

// ---------------------------------------------------------------- gated RMSNorm: y = norm(o*silu(z))*w (bf16, in place over z)
__global__ __launch_bounds__(256) void k_gatenorm(const bf16* __restrict__ o,
                                                  const bf16* __restrict__ z,
                                                  const float* __restrict__ norm_w,
                                                  bf16* __restrict__ y) {
  int row = blockIdx.x * 4 + (threadIdx.x >> 6);  // row = t*32 + h
  int lane = threadIdx.x & 63;
  int i0 = lane * 2;
  bf16x2 ov = *(const bf16x2*)(o + (size_t)row * 128 + i0);
  bf16x2 zv = *(const bf16x2*)(z + (size_t)row * 128 + i0);
  float zf0 = (float)zv[0], zf1 = (float)zv[1];
  float y0 = (float)ov[0] * (zf0 / (1.f + __expf(-zf0)));
  float y1 = (float)ov[1] * (zf1 / (1.f + __expf(-zf1)));
  float ss = y0 * y0 + y1 * y1;
#pragma unroll
  for (int off = 1; off < 64; off <<= 1) ss += __shfl_xor(ss, off);
  float scale = rsqrtf(ss * (1.f / 128.f) + EPS_F);
  float2 nw = *(const float2*)(norm_w + i0);
  bf16x2 out;
  out[0] = (bf16)(y0 * scale * nw.x);
  out[1] = (bf16)(y1 * scale * nw.y);
  *(bf16x2*)(y + (size_t)row * 128 + i0) = out;
}

// ---------------------------------------------------------------- launch
extern "C" void kernel_launch(void* const* d_in, const int* in_sizes, int n_in,
                              void* d_out, int out_size, void* d_ws, size_t ws_size,
                              hipStream_t stream) {
  const float* x = (const float*)d_in[0];
  const int* cu = (const int*)d_in[1];
  const float* Wqkv = (const float*)d_in[2];
  const float* Wz = (const float*)d_in[3];
  const float* Wa = (const float*)d_in[4];
  const float* Wb = (const float*)d_in[5];
  const float* conv_w = (const float*)d_in[6];
  const float* A_log = (const float*)d_in[7];
  const float* dt_bias = (const float*)d_in[8];
  const float* norm_w = (const float*)d_in[9];
  const float* Wout = (const float*)d_in[10];
  float* out = (float*)d_out;
  const int nseq = in_sizes[1] - 1;

  // ---- workspace layout (bytes), total 242 MiB of the 256 MiB budget ----
  const size_t MB = 1024 * 1024;
  char* ws = (char*)d_ws;
  bf16* x16   = (bf16*)(ws + 0);          // 32 MiB  [0,32)
  bf16* WtS   = (bf16*)(ws + 32 * MB);    // 16 MiB  [32,48)  transpose slot (reused 4x)
  bf16* qn    = (bf16*)(ws + 48 * MB);    // 32 MiB  [48,80)
  bf16* kn    = (bf16*)(ws + 80 * MB);    // 32 MiB  [80,112)
  bf16* bigA  = (bf16*)(ws + 112 * MB);   // 64 MiB  [112,176) qk-conv-in -> v-conv-in -> o
  bf16* vbuf  = (bf16*)(ws + 176 * MB);   // 64 MiB  [176,240)
  float* gb   = (float*)(ws + 240 * MB);  // 2 MiB   [240,242)
  bf16* z16   = qn;                       // 64 MiB overlay [48,112) (qn+kn dead after scan)
  bf16* o16   = bigA;
  bf16* y16   = z16;

  if (242 * MB > ws_size) {
    fprintf(stderr, "WORKSPACE TOO SMALL: need %zu, have %zu\n", 242 * MB, ws_size);
    return;
  }

  // 1. x -> bf16
  k_convert<<<(L_SEQ * DIM_ / 4 + 255) / 256, 256, 0, stream>>>((const float4*)x, (bf16x4*)x16,
                                                                L_SEQ * DIM_ / 4);
  // 2. gates (independent, reads fp32 x)
  k_gates<<<L_SEQ / 4, 256, 0, stream>>>(x, Wa, Wb, A_log, dt_bias, gb);

  // 3. qk half: transpose, GEMM, conv
  k_transpose_cvt<<<dim3(4096 / 32, DIM_ / 32), 256, 0, stream>>>(Wqkv, WtS, DIM_, CONV_DIM_, 0);
  k_gemm_bt<1><<<dim3(4096 / 128, L_SEQ / 128), 256, 0, stream>>>(x16, WtS, bigA, L_SEQ, 4096, DIM_);
  k_conv<0><<<dim3(L_SEQ, 32), 128, 0, stream>>>(bigA, conv_w, cu, nseq, qn, kn, vbuf);

  // 4. v half: transpose, GEMM, conv
  k_transpose_cvt<<<dim3(4096 / 32, DIM_ / 32), 256, 0, stream>>>(Wqkv, WtS, DIM_, CONV_DIM_, 4096);
  k_gemm_bt<1><<<dim3(4096 / 128, L_SEQ / 128), 256, 0, stream>>>(x16, WtS, bigA, L_SEQ, 4096, DIM_);
  k_conv<1><<<dim3(L_SEQ, 32), 128, 0, stream>>>(bigA, conv_w, cu, nseq, qn, kn, vbuf);

  // 5. chunked MFMA scan -> o16 (overlays bigA, dead after conv_v)
  k_scan_chunk<<<dim3(2, HV_, nseq), 256, 0, stream>>>(qn, kn, vbuf, gb, cu, o16);

  // 6. z GEMM (overlays qn/kn, dead after scan)
  k_transpose_cvt<<<dim3(4096 / 32, DIM_ / 32), 256, 0, stream>>>(Wz, WtS, DIM_, 4096, 0);
  k_gemm_bt<1><<<dim3(4096 / 128, L_SEQ / 128), 256, 0, stream>>>(x16, WtS, z16, L_SEQ, 4096, DIM_);

  // 7. gated RMSNorm -> y16 (in place over z16)
  k_gatenorm<<<L_SEQ * HV_ / 4, 256, 0, stream>>>(o16, z16, norm_w, y16);

  // 8. out = y @ Wout
  k_transpose_cvt<<<dim3(DIM_ / 32, 4096 / 32), 256, 0, stream>>>(Wout, WtS, 4096, DIM_, 0);
  k_gemm_bt<0><<<dim3(DIM_ / 128, L_SEQ / 128), 256, 0, stream>>>(y16, WtS, out, L_SEQ, DIM_, 4096);
}

// Round 2
// 2138.984 us; speedup vs baseline: 1.3952x; 1.0767x over previous
//
#include <hip/hip_runtime.h>
#include <hip/hip_bf16.h>
#include <stdint.h>
#include <stdio.h>

#define L_SEQ 8192
#define DIM_ 2048
#define HK_ 16
#define HV_ 32
#define DK_ 128
#define DV_ 128
#define CONV_DIM_ 8192
#define EPS_F 1e-6f

typedef __bf16 bf16;
typedef __bf16 bf16x8 __attribute__((ext_vector_type(8)));
typedef __bf16 bf16x4 __attribute__((ext_vector_type(4)));
typedef __bf16 bf16x2 __attribute__((ext_vector_type(2)));
typedef float f32x4 __attribute__((ext_vector_type(4)));

// ---------------------------------------------------------------- helpers
__device__ __forceinline__ void load_lds16(const void* g, void* l) {
  __builtin_amdgcn_global_load_lds((const __attribute__((address_space(1))) uint32_t*)g,
                                   (__attribute__((address_space(3))) uint32_t*)l,
                                   16, 0, 0);
}

// ---------------------------------------------------------------- fp32 -> bf16 convert (x)
__global__ __launch_bounds__(256) void k_convert(const float4* __restrict__ src,
                                                 bf16x4* __restrict__ dst, int n4) {
#pragma unroll
  for (int it = 0; it < 8; it++) {
    int i = blockIdx.x * 2048 + it * 256 + threadIdx.x;
    if (i >= n4) continue;
    float4 v = src[i];
    bf16x4 o;
    o[0] = (bf16)v.x; o[1] = (bf16)v.y; o[2] = (bf16)v.z; o[3] = (bf16)v.w;
    dst[i] = o;
  }
}

// ---------------------------------------------------------------- W [K][ldW] fp32 (cols n_off..n_off+Nout) -> Wt [Nout][K] bf16
__global__ __launch_bounds__(256) void k_transpose_cvt(const float* __restrict__ W,
                                                       bf16* __restrict__ Wt, int K, int ldW,
                                                       int n_off) {
  __shared__ float tile[32][33];
  int n0 = blockIdx.x * 32, k0 = blockIdx.y * 32;
  int cx = threadIdx.x & 31, ry = threadIdx.x >> 5;  // ry in 0..7
#pragma unroll
  for (int i = 0; i < 4; i++)
    tile[ry + i * 8][cx] = W[(size_t)(k0 + ry + i * 8) * ldW + n_off + n0 + cx];
  __syncthreads();
#pragma unroll
  for (int i = 0; i < 4; i++) {
    int r = ry + i * 8;
    Wt[(size_t)(n0 + r) * K + k0 + cx] = (bf16)tile[cx][r];
  }
}

// ---------------------------------------------------------------- bf16 MFMA GEMM: C[M,N] = A[M,K] @ Bt[N,K]^T
template <int BF16_OUT>
__global__ __launch_bounds__(256) void k_gemm_bt(const bf16* __restrict__ A,
                                                 const bf16* __restrict__ Bt,
                                                 void* __restrict__ Cout,
                                                 int M, int N, int K) {
  __shared__ __align__(16) bf16 la[4096];  // [kchunk 4][row 128][8]
  __shared__ __align__(16) bf16 lb[4096];
  const int tid = threadIdx.x;
  const int lane = tid & 63;
  const int wave = tid >> 6;
  const int wm = wave >> 1, wn = wave & 1;
  const int bm = blockIdx.y << 7, bn = blockIdx.x << 7;

  f32x4 acc[4][4];
#pragma unroll
  for (int i = 0; i < 4; i++)
#pragma unroll
    for (int j = 0; j < 4; j++) acc[i][j] = (f32x4){0.f, 0.f, 0.f, 0.f};

  const bf16* Ag = A + (size_t)(bm + lane) * K + wave * 8;
  const bf16* Bg = Bt + (size_t)(bn + lane) * K + wave * 8;
  bf16* lA = la + wave * 1024;
  bf16* lB = lb + wave * 1024;
  const size_t rowskip = (size_t)64 * K;

  const int chunk = lane >> 4;
  const int rr = lane & 15;
  const bf16* fa = la + chunk * 1024 + (wm * 64 + rr) * 8;
  const bf16* fb = lb + chunk * 1024 + (wn * 64 + rr) * 8;

  for (int k0 = 0; k0 < K; k0 += 32) {
    __syncthreads();
    load_lds16(Ag + k0, lA);
    load_lds16(Ag + k0 + rowskip, lA + 512);
    load_lds16(Bg + k0, lB);
    load_lds16(Bg + k0 + rowskip, lB + 512);
    __syncthreads();
    bf16x8 af[4], bfr[4];
#pragma unroll
    for (int i = 0; i < 4; i++) {
      af[i] = *(const bf16x8*)(fa + i * 16 * 8);
      bfr[i] = *(const bf16x8*)(fb + i * 16 * 8);
    }
#pragma unroll
    for (int mi = 0; mi < 4; mi++)
#pragma unroll
      for (int ni = 0; ni < 4; ni++)
        acc[mi][ni] = __builtin_amdgcn_mfma_f32_16x16x32_bf16(af[mi], bfr[ni], acc[mi][ni], 0, 0, 0);
  }

  const int col = bn + wn * 64 + rr;
  const int row0 = bm + wm * 64 + (lane >> 4) * 4;
#pragma unroll
  for (int mi = 0; mi < 4; mi++)
#pragma unroll
    for (int ni = 0; ni < 4; ni++)
#pragma unroll
      for (int r = 0; r < 4; r++) {
        int rowi = row0 + mi * 16 + r;
        int coli = col + ni * 16;
        if (BF16_OUT)
          ((bf16*)Cout)[(size_t)rowi * N + coli] = (bf16)acc[mi][ni][r];
        else
          ((float*)Cout)[(size_t)rowi * N + coli] = acc[mi][ni][r];
      }
}

// ---------------------------------------------------------------- gates: a,b GEMV + g(log-decay)/beta
// gb layout: [t][0..31]=g (LOG decay, nats), [t][32..63]=beta
__global__ __launch_bounds__(256) void k_gates(const float* __restrict__ x,
                                               const float* __restrict__ Wa,
                                               const float* __restrict__ Wb,
                                               const float* __restrict__ A_log,
                                               const float* __restrict__ dt_bias,
                                               float* __restrict__ gb) {
  int t = blockIdx.x * 4 + (threadIdx.x >> 6);
  int lane = threadIdx.x & 63;
  int h = lane & 31;
  int isB = lane >> 5;
  const float* W = isB ? Wb : Wa;
  const float* xr = x + (size_t)t * DIM_;
  float a0 = 0.f, a1 = 0.f, a2 = 0.f, a3 = 0.f;
  for (int kk = 0; kk < DIM_; kk += 4) {
    float4 xv = *(const float4*)(xr + kk);
    a0 += xv.x * W[(kk + 0) * 32 + h];
    a1 += xv.y * W[(kk + 1) * 32 + h];
    a2 += xv.z * W[(kk + 2) * 32 + h];
    a3 += xv.w * W[(kk + 3) * 32 + h];
  }
  float acc = (a0 + a1) + (a2 + a3);
  if (isB) {
    gb[(size_t)t * 64 + 32 + h] = 1.f / (1.f + expf(-acc));
  } else {
    float ag = acc + dt_bias[h];
    float sp = (ag > 20.f) ? ag : log1pf(expf(ag));
    gb[(size_t)t * 64 + h] = -expf(A_log[h]) * sp;  // log decay (<= 0)
  }
}

// ---------------------------------------------------------------- conv + silu (+ l2norm for q/k)
// 8 timesteps per block (grid fattened: 32768 blocks instead of 262144)
template <int IS_V>
__global__ __launch_bounds__(128) void k_conv(const bf16* __restrict__ src,
                                              const float* __restrict__ conv_w,
                                              const int* __restrict__ cu, int nseq,
                                              bf16* __restrict__ qn, bf16* __restrict__ kn,
                                              bf16* __restrict__ v) {
  __shared__ float red[2];
  const int grp = blockIdx.y;  // 0..31
  const int c = grp * 128 + threadIdx.x;
  float4 w = *(const float4*)(conv_w + (size_t)(c + (IS_V ? 4096 : 0)) * 4);
  for (int it = 0; it < 8; it++) {
    int t = blockIdx.x * 8 + it;
    int start = 0;
    for (int s = 0; s < nseq; s++) {
      int a = cu[s];
      if (a <= t) start = a;
    }
    float accv = 0.f;
#pragma unroll
    for (int i = 0; i < 4; i++) {
      int tp = t - 3 + i;
      if (tp >= start) {
        float wv = (i == 0) ? w.x : (i == 1) ? w.y : (i == 2) ? w.z : w.w;
        accv += wv * (float)src[(size_t)tp * 4096 + c];
      }
    }
    float val = accv / (1.f + __expf(-accv));  // silu
    if (IS_V) {
      v[((size_t)t * HV_ + grp) * DV_ + threadIdx.x] = (bf16)val;
    } else {
      float ss = val * val;
#pragma unroll
      for (int off = 1; off < 64; off <<= 1) ss += __shfl_xor(ss, off);
      if ((threadIdx.x & 63) == 0) red[threadIdx.x >> 6] = ss;
      __syncthreads();
      float tot = red[0] + red[1];
      float scale = rsqrtf(tot + EPS_F);
      if (grp < 16) {
        scale *= 0.08838834764831845f;  // DK^-0.5
        qn[((size_t)t * HK_ + grp) * DK_ + threadIdx.x] = (bf16)(val * scale);
      } else {
        kn[((size_t)t * HK_ + (grp - 16)) * DK_ + threadIdx.x] = (bf16)(val * scale);
      }
      __syncthreads();  // protect red[] reuse next iteration
    }
  }
}

// ================================================================ chunked gated delta scan (WY form, MFMA)
// 8 waves / block (2 waves/SIMD), role-split:
//   group0 (waves 0-3): QK^T + Q*S0, sM build, T1 (scaled K^T), output O
//   group1 (waves 4-7): KK^T + K*S0, sA build, R build
//   substitution: wave0 serial diagonal, waves 1-6 trailing updates
//   state update: all 8 waves (each owns a 16-row dk slice of S)

#define SA_LD 68
#define SUF_LD 65

__device__ __forceinline__ bf16x8 frag256(const bf16* base, int tile, int kk, int lane) {
  int row = tile * 16 + (lane & 15);
  int blk = kk * 4 + (lane >> 4);  // 0..15
  int byte = row * 256 + (((blk & 8) | ((blk & 7) ^ (row & 7))) << 4);
  return *(const bf16x8*)((const char*)base + byte);
}
__device__ __forceinline__ bf16x8 frag128(const bf16* base, int tile, int kk, int lane) {
  int row = tile * 16 + (lane & 15);
  int blk = kk * 4 + (lane >> 4);  // 0..7
  int byte = row * 128 + ((blk ^ (row & 7)) << 4);
  return *(const bf16x8*)((const char*)base + byte);
}
__device__ __forceinline__ bf16x8 ld256v(const bf16* base, int row, int blk) {
  int byte = row * 256 + (((blk & 8) | ((blk & 7) ^ (row & 7))) << 4);
  return *(const bf16x8*)((const char*)base + byte);
}
__device__ __forceinline__ void st128e(bf16* base, int row, int col, float v) {
  int byte = row * 128 + ((((col >> 3) ^ (row & 7)) << 4)) + (col & 7) * 2;
  *(bf16*)((char*)base + byte) = (bf16)v;
}
__device__ __forceinline__ float ld128e(const bf16* base, int row, int col) {
  int byte = row * 128 + ((((col >> 3) ^ (row & 7)) << 4)) + (col & 7) * 2;
  return (float)*(const bf16*)((const char*)base + byte);
}
__device__ __forceinline__ void st256e(bf16* base, int row, int col, float v) {
  int blk = col >> 3;  // 0..15
  int byte = row * 256 + (((blk & 8) | ((blk & 7) ^ (row & 7))) << 4) + (col & 7) * 2;
  *(bf16*)((char*)base + byte) = (bf16)v;
}

__global__ __launch_bounds__(512, 2) void k_scan_chunk(const bf16* __restrict__ qn,
                                                       const bf16* __restrict__ kn,
                                                       const bf16* __restrict__ v,
                                                       const float* __restrict__ gb,
                                                       const int* __restrict__ cu,
                                                       bf16* __restrict__ o) {
  __shared__ __align__(16) bf16 sK[64 * 128];    // [t][dk]  swz256
  __shared__ __align__(16) bf16 sQ[64 * 128];    // [t][dk]  swz256
  __shared__ __align__(16) bf16 sKt[128 * 64];   // [dk][t]  swz128, scaled 2^(G2c-G2t)
  __shared__ __align__(16) bf16 sSt[64 * 128];   // [dv][dk] swz256, state operand copy
  __shared__ __align__(16) bf16 sV[64 * 64];     // [t][dv]  swz128
  __shared__ __align__(16) bf16 sM[64 * 64];     // [t][s]   swz128
  __shared__ __align__(16) bf16 sUt[64 * 64];    // [dv][s]  swz128
  __shared__ float sA[64 * SA_LD];               // [t][s]   fp32
  __shared__ float sUf[64 * SUF_LD];             // [t][dv]  fp32 (R then U)
  __shared__ float sG2[2][64], sB[2][64], sEg[2][64];

  const int h = blockIdx.y;
  const int hk = h >> 1;
  const int seq = blockIdx.z;
  const int dv0 = blockIdx.x * 64;
  const int tid = threadIdx.x;
  const int lane = tid & 63;
  const int wave = tid >> 6;   // 0..7
  const int w4 = wave & 3;
  const int grp = wave >> 2;   // 0: Q-side, 1: K-side
  const int t0 = cu[seq], t1 = cu[seq + 1];
  if (t0 >= t1) return;

  // fp32 state slice in regs: dk row = wave*16 + (lane>>4)*4 + r, dv col = c*16 + (lane&15)
  f32x4 St[4];
#pragma unroll
  for (int c = 0; c < 4; c++) St[c] = (f32x4){0.f, 0.f, 0.f, 0.f};
  ((float4*)sSt)[tid] = (float4){0.f, 0.f, 0.f, 0.f};
  ((float4*)sSt)[tid + 512] = (float4){0.f, 0.f, 0.f, 0.f};

  auto stageKQV = [&](int ts) {
#pragma unroll
    for (int it = 0; it < 2; it++) {
      int Bx = (wave * 2 + it) * 64 + lane;  // 16B block index (1024 total)
      int r = Bx >> 4, bq = Bx & 15;
      int tr = ts + r; if (tr >= t1) tr = t1 - 1;
      int bs = (bq & 8) | ((bq & 7) ^ (r & 7));  // pre-swizzled global block
      size_t go = (size_t)tr * (HK_ * DK_) + hk * DK_ + bs * 8;
      load_lds16(kn + go, (char*)sK + (size_t)(wave * 2 + it) * 1024);
      load_lds16(qn + go, (char*)sQ + (size_t)(wave * 2 + it) * 1024);
    }
    {
      int Bx = wave * 64 + lane;  // 512 blocks
      int r = Bx >> 3, bq = Bx & 7;
      int tr = ts + r; if (tr >= t1) tr = t1 - 1;
      int bs = bq ^ (r & 7);
      load_lds16(v + (size_t)tr * (HV_ * DV_) + h * DV_ + dv0 + bs * 8,
                 (char*)sV + (size_t)wave * 1024);
    }
  };

  auto prefix = [&](int ts, int pb) {  // one wave: load g/beta, log2 cumsum
    int tr = ts + lane;
    float gv = 0.f, bv = 0.f;
    if (tr < t1) {
      gv = gb[(size_t)tr * 64 + h] * 1.44269504088896f;
      bv = gb[(size_t)tr * 64 + 32 + h];
    }
    float ps = gv;
#pragma unroll
    for (int off = 1; off < 64; off <<= 1) {
      float tmp = __shfl_up(ps, off);
      if (lane >= off) ps += tmp;
    }
    sG2[pb][lane] = ps;
    sB[pb][lane] = bv;
    sEg[pb][lane] = exp2f(ps);
  };

  int buf = 0;
  stageKQV(t0);
  if (wave == 0) prefix(t0, 0);
  __syncthreads();

  bool first = true;
  for (int ts = t0; ts < t1; ts += 64) {
    const bool haveNext = (ts + 64 < t1);
    const float* G2 = sG2[buf];
    const float* Bt = sB[buf];
    const float* Eg = sEg[buf];

    // ---- phase 1: group0: QK^T (lower) + Q*S0 ; group1: KK^T (lower) + K*S0 ----
    f32x4 accA[4], accB[4];
#pragma unroll
    for (int c = 0; c < 4; c++) {
      accA[c] = (f32x4){0.f, 0.f, 0.f, 0.f};
      accB[c] = (f32x4){0.f, 0.f, 0.f, 0.f};
    }
    const bf16* opA = grp ? sK : sQ;
#pragma unroll
    for (int kk = 0; kk < 4; kk++) {
      bf16x8 af = frag256(opA, w4, kk, lane);
#pragma unroll
      for (int c = 0; c < 4; c++) {
        if (c <= w4) {
          bf16x8 bk = frag256(sK, c, kk, lane);
          accA[c] = __builtin_amdgcn_mfma_f32_16x16x32_bf16(af, bk, accA[c], 0, 0, 0);
        }
        if (!first) {
          bf16x8 bs_ = frag256(sSt, c, kk, lane);
          accB[c] = __builtin_amdgcn_mfma_f32_16x16x32_bf16(af, bs_, accB[c], 0, 0, 0);
        }
      }
    }

    // ---- mask/scale phase (role split) ----
    const float G2c = G2[63];
    const int li = lane & 15, lh = lane >> 4;
    {
      float g2s[4];
#pragma unroll
      for (int c = 0; c < 4; c++) g2s[c] = G2[c * 16 + li];
      if (grp) {
        // group1: sA (fp32) + R -> sUf
#pragma unroll
        for (int r = 0; r < 4; r++) {
          const int t = w4 * 16 + lh * 4 + r;
          const float g2t = G2[t], btv = Bt[t], egt = Eg[t];
#pragma unroll
          for (int c = 0; c < 4; c++) {
            const int s = c * 16 + li;
            const float e = exp2f(g2t - g2s[c]);
            sA[t * SA_LD + s] = (s < t) ? btv * e * accA[c][r] : 0.f;
            sUf[t * SUF_LD + s] = btv * (ld128e(sV, t, s) - egt * accB[c][r]);
          }
        }
      } else {
        // group0: sM (bf16)
#pragma unroll
        for (int r = 0; r < 4; r++) {
          const int t = w4 * 16 + lh * 4 + r;
          const float g2t = G2[t];
#pragma unroll
          for (int c = 0; c < 4; c++) {
            const int s = c * 16 + li;
            const float e = exp2f(g2t - g2s[c]);
            st128e(sM, t, s, (s <= t) ? e * accA[c][r] : 0.f);
          }
        }
        // T1: sKt[dk][t] = K[t][dk] * 2^(G2c - G2t)  (group0, 32 dk per wave)
        const int tt = lane;
        const float sc = exp2f(G2c - G2[tt]);
#pragma unroll
        for (int i = 0; i < 4; i++) {
          int dk0 = w4 * 32 + i * 8;
          bf16x8 kv = ld256v(sK, tt, w4 * 4 + i);
#pragma unroll
          for (int j = 0; j < 8; j++) st128e(sKt, dk0 + j, tt, (float)kv[j] * sc);
        }
      }
    }
    __syncthreads();

    // ---- issue next-chunk staging early (hides HBM under substitution) ----
    if (haveNext) {
      stageKQV(ts + 64);
      if (wave == 7) prefix(ts + 64, buf ^ 1);
    }

    // ---- forward substitution: (I+A) U = R, 16-row blocks ----
    for (int b = 0; b < 4; b++) {
      if (wave == 0) {
        const int b16o = b * 16;
        float u[16];
#pragma unroll
        for (int i = 0; i < 16; i++) {
          const int t = b16o + i;
          float x = sUf[t * SUF_LD + lane];
          const float* Ar = &sA[t * SA_LD + b16o];
#pragma unroll
          for (int j = 0; j < i; j++) x -= Ar[j] * u[j];
          u[i] = x;
          sUf[t * SUF_LD + lane] = x;
        }
      }
      __syncthreads();
      if (b < 3) {
        if (wave >= 1 && wave <= 6) {  // wave 7 may be doing next-chunk prefix
          const int b16o = b * 16;
          float us[16];
#pragma unroll
          for (int j = 0; j < 16; j++) us[j] = sUf[(b16o + j) * SUF_LD + lane];
          for (int t = b16o + 16 + (wave - 1); t < 64; t += 6) {
            float x = sUf[t * SUF_LD + lane];
            const float* Ar = &sA[t * SA_LD + b16o];
#pragma unroll
            for (int j = 0; j < 16; j++) x -= Ar[j] * us[j];
            sUf[t * SUF_LD + lane] = x;
          }
        }
        __syncthreads();
      }
    }

    // ---- T2: sUt[dv][s] = U[s][dv] (bf16), 8 dv rows per wave ----
    {
      const int s = lane;
#pragma unroll
      for (int i = 0; i < 8; i++) {
        int dvv = wave * 8 + i;
        st128e(sUt, dvv, s, sUf[s * SUF_LD + dvv]);
      }
    }
    __syncthreads();

    // ---- output (group0): O = 2^G2t * (Q S0) + M U ----
    if (!grp) {
      f32x4 aO[4];
#pragma unroll
      for (int c = 0; c < 4; c++)
#pragma unroll
        for (int r = 0; r < 4; r++)
          aO[c][r] = Eg[w4 * 16 + lh * 4 + r] * accB[c][r];
#pragma unroll
      for (int kk = 0; kk < 2; kk++) {
        bf16x8 am = frag128(sM, w4, kk, lane);
#pragma unroll
        for (int c = 0; c < 4; c++) {
          bf16x8 bu = frag128(sUt, c, kk, lane);
          aO[c] = __builtin_amdgcn_mfma_f32_16x16x32_bf16(am, bu, aO[c], 0, 0, 0);
        }
      }
#pragma unroll
      for (int r = 0; r < 4; r++) {
        const int t = w4 * 16 + lh * 4 + r;
        if (ts + t < t1) {
#pragma unroll
          for (int c = 0; c < 4; c++)
            o[((size_t)(ts + t) * HV_ + h) * DV_ + dv0 + c * 16 + li] = (bf16)aO[c][r];
        }
      }
    }

    // ---- state update (all 8 waves): S = 2^G2c * S + Kt' U ----
    {
      const float egc = Eg[63];
#pragma unroll
      for (int c = 0; c < 4; c++)
#pragma unroll
        for (int r = 0; r < 4; r++) St[c][r] *= egc;
#pragma unroll
      for (int kk = 0; kk < 2; kk++) {
        bf16x8 akt = frag128(sKt, wave, kk, lane);
#pragma unroll
        for (int c = 0; c < 4; c++) {
          bf16x8 bu = frag128(sUt, c, kk, lane);
          St[c] = __builtin_amdgcn_mfma_f32_16x16x32_bf16(akt, bu, St[c], 0, 0, 0);
        }
      }
      // bf16 operand copy for next chunk's K*S0 / Q*S0
#pragma unroll
      for (int c = 0; c < 4; c++)
#pragma unroll
        for (int r = 0; r < 4; r++) {
          int dk = wave * 16 + lh * 4 + r;
          int dvv = c * 16 + li;
          st256e(sSt, dvv, dk, St[c][r]);
        }
    }
    first = false;
    buf ^= 1;
    __syncthreads();  // sSt/sG2[buf] visible; staged DMA drained
  }
}

// ---------------------------------------------------------------- gated RMSNorm: y = norm(o*silu(z))*w
// 16 row-groups per block (grid fattened: 4096 blocks)
__global__ __launch_bounds__(256) void k_gatenorm(const bf16* __restrict__ o,
                                                  const bf16* __restrict__ z,
                                                  const float* __restrict__ norm_w,
                                                  bf16* __restrict__ y) {
  int lane = threadIdx.x & 63;
  int i0 = lane * 2;
  float2 nw = *(const float2*)(norm_w + i0);
#pragma unroll
  for (int it = 0; it < 16; it++) {
    int row = blockIdx.x * 64 + it * 4 + (threadIdx.x >> 6);  // row = t*32 + h
    bf16x2 ov = *(const bf16x2*)(o + (size_t)row * 128 + i0);
    bf16x2 zv = *(const bf16x2*)(z + (size_t)row * 128 + i0);
    float zf0 = (float)zv[0], zf1 = (float)zv[1];
    float y0 = (float)ov[0] * (zf0 / (1.f + __expf(-zf0)));
    float y1 = (float)ov[1] * (zf1 / (1.f + __expf(-zf1)));
    float ss = y0 * y0 + y1 * y1;
#pragma unroll
    for (int off = 1; off < 64; off <<= 1) ss += __shfl_xor(ss, off);
    float scale = rsqrtf(ss * (1.f / 128.f) + EPS_F);
    bf16x2 out;
    out[0] = (bf16)(y0 * scale * nw.x);
    out[1] = (bf16)(y1 * scale * nw.y);
    *(bf16x2*)(y + (size_t)row * 128 + i0) = out;
  }
}

// ---------------------------------------------------------------- launch
extern "C" void kernel_launch(void* const* d_in, const int* in_sizes, int n_in,
                              void* d_out, int out_size, void* d_ws, size_t ws_size,
                              hipStream_t stream) {
  const float* x = (const float*)d_in[0];
  const int* cu = (const int*)d_in[1];
  const float* Wqkv = (const float*)d_in[2];
  const float* Wz = (const float*)d_in[3];
  const float* Wa = (const float*)d_in[4];
  const float* Wb = (const float*)d_in[5];
  const float* conv_w = (const float*)d_in[6];
  const float* A_log = (const float*)d_in[7];
  const float* dt_bias = (const float*)d_in[8];
  const float* norm_w = (const float*)d_in[9];
  const float* Wout = (const float*)d_in[10];
  float* out = (float*)d_out;
  const int nseq = in_sizes[1] - 1;

  // ---- workspace layout (bytes), total 242 MiB of the 256 MiB budget ----
  const size_t MB = 1024 * 1024;
  char* ws = (char*)d_ws;
  bf16* x16   = (bf16*)(ws + 0);          // 32 MiB  [0,32)
  bf16* WtS   = (bf16*)(ws + 32 * MB);    // 16 MiB  [32,48)  transpose slot (reused 4x)
  bf16* qn    = (bf16*)(ws + 48 * MB);    // 32 MiB  [48,80)
  bf16* kn    = (bf16*)(ws + 80 * MB);    // 32 MiB  [80,112)
  bf16* bigA  = (bf16*)(ws + 112 * MB);   // 64 MiB  [112,176) qk-conv-in -> v-conv-in -> o
  bf16* vbuf  = (bf16*)(ws + 176 * MB);   // 64 MiB  [176,240)
  float* gb   = (float*)(ws + 240 * MB);  // 2 MiB   [240,242)
  bf16* z16   = qn;                       // 64 MiB overlay [48,112) (qn+kn dead after scan)
  bf16* o16   = bigA;
  bf16* y16   = z16;

  if (242 * MB > ws_size) {
    fprintf(stderr, "WORKSPACE TOO SMALL: need %zu, have %zu\n", 242 * MB, ws_size);
    return;
  }

  // 1. x -> bf16
  k_convert<<<L_SEQ * DIM_ / 4 / 2048, 256, 0, stream>>>((const float4*)x, (bf16x4*)x16,
                                                         L_SEQ * DIM_ / 4);
  // 2. gates (independent, reads fp32 x)
  k_gates<<<L_SEQ / 4, 256, 0, stream>>>(x, Wa, Wb, A_log, dt_bias, gb);

  // 3. qk half: transpose, GEMM, conv
  k_transpose_cvt<<<dim3(4096 / 32, DIM_ / 32), 256, 0, stream>>>(Wqkv, WtS, DIM_, CONV_DIM_, 0);
  k_gemm_bt<1><<<dim3(4096 / 128, L_SEQ / 128), 256, 0, stream>>>(x16, WtS, bigA, L_SEQ, 4096, DIM_);
  k_conv<0><<<dim3(L_SEQ / 8, 32), 128, 0, stream>>>(bigA, conv_w, cu, nseq, qn, kn, vbuf);

  // 4. v half: transpose, GEMM, conv
  k_transpose_cvt<<<dim3(4096 / 32, DIM_ / 32), 256, 0, stream>>>(Wqkv, WtS, DIM_, CONV_DIM_, 4096);
  k_gemm_bt<1><<<dim3(4096 / 128, L_SEQ / 128), 256, 0, stream>>>(x16, WtS, bigA, L_SEQ, 4096, DIM_);
  k_conv<1><<<dim3(L_SEQ / 8, 32), 128, 0, stream>>>(bigA, conv_w, cu, nseq, qn, kn, vbuf);

  // 5. chunked MFMA scan -> o16 (overlays bigA, dead after conv_v)
  k_scan_chunk<<<dim3(2, HV_, nseq), 512, 0, stream>>>(qn, kn, vbuf, gb, cu, o16);

  // 6. z GEMM (overlays qn/kn, dead after scan)
  k_transpose_cvt<<<dim3(4096 / 32, DIM_ / 32), 256, 0, stream>>>(Wz, WtS, DIM_, 4096, 0);
  k_gemm_bt<1><<<dim3(4096 / 128, L_SEQ / 128), 256, 0, stream>>>(x16, WtS, z16, L_SEQ, 4096, DIM_);

  // 7. gated RMSNorm -> y16 (in place over z16)
  k_gatenorm<<<L_SEQ * HV_ / 64, 256, 0, stream>>>(o16, z16, norm_w, y16);

  // 8. out = y @ Wout
  k_transpose_cvt<<<dim3(DIM_ / 32, 4096 / 32), 256, 0, stream>>>(Wout, WtS, 4096, DIM_, 0);
  k_gemm_bt<0><<<dim3(DIM_ / 128, L_SEQ / 128), 256, 0, stream>>>(y16, WtS, out, L_SEQ, DIM_, 4096);
}